// Round 10
// baseline (185.881 us; speedup 1.0000x reference)
//
#include <hip/hip_runtime.h>
#include <math.h>

#define BATCH 2048
#define FEAT  2048
#define LUTSZ 64

typedef float f32x2 __attribute__((ext_vector_type(2)));
typedef int   i32x2 __attribute__((ext_vector_type(2)));

// ---------------------------------------------------------------------------
// Round-10: attack the L1-miss path of the divergent slut gather.
//
// r9 diagnosis: all pipes ~20% busy across 5 structures stuck at 130-175us.
// The common op is the divergent lut gather (64 lanes x 64 distinct 64B
// lines, slut 512KB >> L1 32KB -> every lane ~a miss). 768 gathers/CU x
// ~400cyc CU-shared miss-queue occupancy ~= 128us = the wall.
//
// Changes vs r9 (numerics byte-identical):
//  * slut/lut3 gather via __builtin_nontemporal_load -> no L1 allocation,
//    no line fills, no miss-queue occupancy per 64B line for 4B of use.
//  * r loads + out stores non-temporal (stream-once, 302MB) -> stop
//    thrashing L1. connect stays cached (48KB/layer, reused by all blocks).
//  * phase-split per layer: phase A computes all 8 chunk idx values
//    (ballot transpose, proven r9) -> phase B issues 8 slut gathers
//    back-to-back (8-deep MLP) -> stores. Full unroll, all reg indices
//    compile-time.
// ---------------------------------------------------------------------------

struct RC { f32x2 r0, r1, r2; i32x2 c0, c1, c2; };

// Block barrier that drains LDS but leaves (read-only) vmem loads in flight.
__device__ __forceinline__ void block_sync_keep_vm() {
    __builtin_amdgcn_sched_barrier(0);
    asm volatile("s_waitcnt lgkmcnt(0)\n\ts_barrier" ::: "memory");
    __builtin_amdgcn_sched_barrier(0);
}

__device__ __forceinline__ RC load_rc(const float* __restrict__ r,
                                      const int* __restrict__ c,
                                      int b, int fw, int lane) {
    const f32x2* rg = reinterpret_cast<const f32x2*>(
        r + ((size_t)b * FEAT + fw) * 6);
    const i32x2* cg = reinterpret_cast<const i32x2*>(c + (size_t)fw * 6);
    RC x;
    x.r0 = __builtin_nontemporal_load(rg + lane);        // r: stream-once, NT
    x.r1 = __builtin_nontemporal_load(rg + 64 + lane);
    x.r2 = __builtin_nontemporal_load(rg + 128 + lane);
    x.c0 = cg[lane];                                     // c: hot, keep cached
    x.c1 = cg[64 + lane];
    x.c2 = cg[128 + lane];
    return x;
}

__global__ __launch_bounds__(256) void sigmoid_lut_kernel(
    const float* __restrict__ lut1, const float* __restrict__ lut2,
    float* __restrict__ slut1, float* __restrict__ slut2)
{
    const int n = FEAT * LUTSZ;
    int i = blockIdx.x * 256 + threadIdx.x;
    if (i < n) {
        float v = lut1[i];
        float e = (float)exp(-(double)v);     // correctly-rounded f32 exp
        slut1[i] = 1.0f / (1.0f + e);         // f32 IEEE chain (matches np)
    } else {
        i -= n;
        float v = lut2[i];
        float e = (float)exp(-(double)v);
        slut2[i] = 1.0f / (1.0f + e);
    }
}

// a = chunk k data, b_ = chunk k+1 data (registers, scrambled layout).
// On exit (LAST=false): a,b_ hold the NEXT layer's chunks 0,1.
template<int TO_GLOBAL, bool LAST>
__device__ __forceinline__ void layer_run(
    RC& a, RC& b_,
    const float* __restrict__ rcur, const int* __restrict__ ccur,
    const float* __restrict__ rnxt, const int* __restrict__ cnxt,
    const float* __restrict__ lut,
    const float* xsrc, float* ydst, float* __restrict__ outg,
    int b, int lane, int w)
{
    int idxs[8];   // compile-time indexed only (full unroll)

    // ---- phase A: all 8 chunks' indices via ballot transpose ----
    #pragma unroll
    for (int k = 0; k < 8; ++k) {
        // prefetch chunk k+2 (crosses into next layer at k>=6)
        RC n;
        if (k < 6) {
            n = load_rc(rcur, ccur, b, ((k + 2) & 7) * 256 + w * 64, lane);
        } else if (!LAST) {
            n = load_rc(rnxt, cnxt, b, ((k + 2) & 7) * 256 + w * 64, lane);
        }

        // lane l holds slice elements {2l, 2l+1, 2l+128, 2l+129, 2l+256, 2l+257}
        const unsigned long long B0 = __ballot(xsrc[a.c0[0]] >= a.r0[0]);
        const unsigned long long B1 = __ballot(xsrc[a.c0[1]] >= a.r0[1]);
        const unsigned long long B2 = __ballot(xsrc[a.c1[0]] >= a.r1[0]);
        const unsigned long long B3 = __ballot(xsrc[a.c1[1]] >= a.r1[1]);
        const unsigned long long B4 = __ballot(xsrc[a.c2[0]] >= a.r2[0]);
        const unsigned long long B5 = __ballot(xsrc[a.c2[1]] >= a.r2[1]);

        // owner lane phi needs elements e = 6*phi + j, j=0..5:
        //   ballot index 2*(e>>7) + (e&1), bit position (e&127)>>1
        int idx = 0;
        #pragma unroll
        for (int j = 0; j < 6; ++j) {
            const int e = 6 * lane + j;          // 6*lane even => e&1 == j&1
            const int g = e >> 7;                // 0,1,2 (per-lane)
            const unsigned long long src =
                (j & 1) ? ((g == 0) ? B1 : (g == 1) ? B3 : B5)
                        : ((g == 0) ? B0 : (g == 1) ? B2 : B4);
            idx |= (int)((src >> ((e & 127) >> 1)) & 1ull) << j;
        }
        idxs[k] = idx;

        a = b_;
        if (!(LAST && k >= 6)) b_ = n;
    }

    // ---- phase B: 8 slut gathers back-to-back (8-deep MLP), then stores ----
    float vals[8];
    #pragma unroll
    for (int k = 0; k < 8; ++k) {
        const int f = k * 256 + w * 64 + lane;
        vals[k] = __builtin_nontemporal_load(
            lut + (size_t)f * LUTSZ + idxs[k]);
    }
    #pragma unroll
    for (int k = 0; k < 8; ++k) {
        const int f = k * 256 + w * 64 + lane;
        if (TO_GLOBAL) {
            __builtin_nontemporal_store(vals[k], outg + (size_t)b * FEAT + f);
        } else {
            ydst[f] = vals[k];
        }
    }
}

__global__ __launch_bounds__(256) void fused3_nt(
    const float* __restrict__ inputs,
    const float* __restrict__ r1, const float* __restrict__ r2,
    const float* __restrict__ r3,
    const float* __restrict__ slut1, const float* __restrict__ slut2,
    const float* __restrict__ lut3,
    const int* __restrict__ c1, const int* __restrict__ c2,
    const int* __restrict__ c3,
    float* __restrict__ out)
{
    __shared__ float xs[FEAT];   // 8 KiB
    __shared__ float ys[FEAT];   // 8 KiB   -> 16 KiB total

    const int b    = blockIdx.x;
    const int tid  = threadIdx.x;
    const int lane = tid & 63;
    const int w    = tid >> 6;

    // Prefetch layer-1 chunks 0,1 first (latency hides under xs staging).
    RC a  = load_rc(r1, c1, b, 0 * 256 + w * 64, lane);
    RC b_ = load_rc(r1, c1, b, 1 * 256 + w * 64, lane);

    // Stage input row -> xs with the exact f32 transform (v+1.0f)*0.5f.
    {
        const float4* xrow = reinterpret_cast<const float4*>(
            inputs + (size_t)b * FEAT);
        float4* xs4 = reinterpret_cast<float4*>(xs);
        #pragma unroll
        for (int i = tid; i < FEAT / 4; i += 256) {
            float4 v = xrow[i];
            v.x = (v.x + 1.0f) * 0.5f;
            v.y = (v.y + 1.0f) * 0.5f;
            v.z = (v.z + 1.0f) * 0.5f;
            v.w = (v.w + 1.0f) * 0.5f;
            xs4[i] = v;
        }
    }
    block_sync_keep_vm();

    layer_run<0, false>(a, b_, r1, c1, r2, c2, slut1, xs, ys, nullptr,
                        b, lane, w);
    block_sync_keep_vm();
    layer_run<0, false>(a, b_, r2, c2, r3, c3, slut2, ys, xs, nullptr,
                        b, lane, w);
    block_sync_keep_vm();
    layer_run<1, true>(a, b_, r3, c3, r3, c3, lut3, xs, nullptr, out,
                       b, lane, w);
}

extern "C" void kernel_launch(void* const* d_in, const int* in_sizes, int n_in,
                              void* d_out, int out_size, void* d_ws, size_t ws_size,
                              hipStream_t stream) {
    const float* inputs = (const float*)d_in[0];
    const float* r1     = (const float*)d_in[1];
    const float* r2     = (const float*)d_in[2];
    const float* r3     = (const float*)d_in[3];
    const float* lut1   = (const float*)d_in[4];
    const float* lut2   = (const float*)d_in[5];
    const float* lut3   = (const float*)d_in[6];
    const int*   c1     = (const int*)d_in[7];
    const int*   c2     = (const int*)d_in[8];
    const int*   c3     = (const int*)d_in[9];
    float* out = (float*)d_out;

    float* slut1 = (float*)d_ws;                       // [FEAT, 64]
    float* slut2 = slut1 + (size_t)FEAT * LUTSZ;       // [FEAT, 64]

    sigmoid_lut_kernel<<<dim3(2 * FEAT * LUTSZ / 256), dim3(256), 0, stream>>>(
        lut1, lut2, slut1, slut2);

    fused3_nt<<<dim3(BATCH), dim3(256), 0, stream>>>(
        inputs, r1, r2, r3, slut1, slut2, lut3, c1, c2, c3, out);
}

// Round 11
// 139.387 us; speedup vs baseline: 1.3336x; 1.3336x over previous
//
#include <hip/hip_runtime.h>
#include <math.h>

#define BATCH  2048
#define FEAT   2048
#define LUTSZ  64
#define TF     256          // features per tile
#define NCH    4            // TF/64 chunks per row per wave
#define GROUPS 32           // batch groups
#define RPB    64           // rows per block  = BATCH/GROUPS
#define WAVES  8
#define RPW    8            // rows per wave   = RPB/WAVES

typedef float f32x2 __attribute__((ext_vector_type(2)));
typedef int   i32x2 __attribute__((ext_vector_type(2)));
typedef float f32x4 __attribute__((ext_vector_type(4)));

// ---------------------------------------------------------------------------
// Round-11: feature-tile structure -- the divergent GLOBAL lut gather (the
// ~130us L2-request-rate wall common to every prior structure) becomes an
// LDS gather.
//
//  * grid 8 tiles x 32 groups = 256 blocks x 512 thr (8 waves) = 1 block/CU.
//  * LDS: 64KB lut tile (sigmoid applied DURING staging, f32 chain intact,
//    no prologue kernel, no extra ws) + 8 x 8KB wave-private x rows = 128KB.
//  * per wave, per row: prefetch next row x/r into regs (issue-early,
//    write-late), fence (r7 discipline), ballot-transpose compares (r9,
//    verified), LDS slut gather, coalesced store. No block barriers in loop.
//  * connect in registers once per block (removes ~50MB redundant traffic).
//
// Numerics locked (absmax 0.0 in r4/r5/r7/r8/r9): layer-1 (v+1.0f)*0.5f;
// sigmoid = 1.0f/(1.0f + RN32(exp_f64(-v))); compares in f32; NO nontemporal.
// ---------------------------------------------------------------------------

__device__ __forceinline__ void wave_fence() {
    __builtin_amdgcn_sched_barrier(0);
    __builtin_amdgcn_wave_barrier();
    __builtin_amdgcn_sched_barrier(0);
}

template<int L>   // 0: transform-in + sigmoid-lut; 1: sigmoid-lut; 2: raw lut
__global__ __launch_bounds__(512, 2) void lut_tile_kernel(
    const float* __restrict__ xin, const float* __restrict__ rr,
    const int* __restrict__ connect, const float* __restrict__ lutg,
    float* __restrict__ yout)
{
    __shared__ float sl[TF * LUTSZ];          // 64 KiB lut tile
    __shared__ f32x4 xr4[WAVES][FEAT / 4];    // 64 KiB wave-private x rows

    const int tile = blockIdx.x;
    const int grp  = blockIdx.y;
    const int f0   = tile * TF;
    const int tid  = threadIdx.x;
    const int lane = tid & 63;
    const int w    = tid >> 6;

    // ---- stage lut tile (+ exact f32-chain sigmoid for L<2) ----
    for (int i = tid; i < TF * LUTSZ; i += 512) {
        float v = lutg[(size_t)f0 * LUTSZ + i];
        if (L < 2) {
            float e = (float)exp(-(double)v);   // correctly-rounded f32 exp
            v = 1.0f / (1.0f + e);              // f32 IEEE chain
        }
        sl[i] = v;
    }

    // ---- connect regs (scrambled ballot layout), once per block ----
    i32x2 cc[NCH][3];
    #pragma unroll
    for (int t = 0; t < NCH; ++t) {
        const i32x2* cg = reinterpret_cast<const i32x2*>(
            connect + (size_t)(f0 + t * 64) * 6);
        cc[t][0] = cg[lane]; cc[t][1] = cg[64 + lane]; cc[t][2] = cg[128 + lane];
    }

    const int b0 = grp * RPB + w * RPW;
    float* xw = reinterpret_cast<float*>(xr4[w]);

    // ---- prefetch row 0 (x, r) ----
    f32x4 nx[8];
    f32x2 nr[NCH][3];
    {
        const f32x4* xg = reinterpret_cast<const f32x4*>(xin + (size_t)b0 * FEAT);
        #pragma unroll
        for (int j = 0; j < 8; ++j) nx[j] = xg[j * 64 + lane];
        #pragma unroll
        for (int t = 0; t < NCH; ++t) {
            const f32x2* rg = reinterpret_cast<const f32x2*>(
                rr + ((size_t)b0 * FEAT + f0 + t * 64) * 6);
            nr[t][0] = rg[lane]; nr[t][1] = rg[64 + lane]; nr[t][2] = rg[128 + lane];
        }
    }

    __syncthreads();   // sl visible to all waves; no block barriers after this

    for (int i = 0; i < RPW; ++i) {
        const int b = b0 + i;

        // keep current row's r (frees nr for prefetch)
        f32x2 cr[NCH][3];
        #pragma unroll
        for (int t = 0; t < NCH; ++t) {
            cr[t][0] = nr[t][0]; cr[t][1] = nr[t][1]; cr[t][2] = nr[t][2];
        }

        // ---- write x row to wave-private LDS (WAR fence vs prev gathers) ----
        wave_fence();
        #pragma unroll
        for (int j = 0; j < 8; ++j) {
            f32x4 v = nx[j];
            if (L == 0) v = (v + 1.0f) * 0.5f;   // exact f32 chain, layer 1
            xr4[w][j * 64 + lane] = v;
        }
        wave_fence();

        // ---- prefetch next row (latency hides under chunk compute) ----
        if (i + 1 < RPW) {
            const int bn = b + 1;
            const f32x4* xg = reinterpret_cast<const f32x4*>(
                xin + (size_t)bn * FEAT);
            #pragma unroll
            for (int j = 0; j < 8; ++j) nx[j] = xg[j * 64 + lane];
            #pragma unroll
            for (int t = 0; t < NCH; ++t) {
                const f32x2* rg = reinterpret_cast<const f32x2*>(
                    rr + ((size_t)bn * FEAT + f0 + t * 64) * 6);
                nr[t][0] = rg[lane]; nr[t][1] = rg[64 + lane];
                nr[t][2] = rg[128 + lane];
            }
        }

        // ---- 4 chunks: ballot transpose (r9-verified) + LDS lut gather ----
        #pragma unroll
        for (int t = 0; t < NCH; ++t) {
            const unsigned long long B0 = __ballot(xw[cc[t][0][0]] >= cr[t][0][0]);
            const unsigned long long B1 = __ballot(xw[cc[t][0][1]] >= cr[t][0][1]);
            const unsigned long long B2 = __ballot(xw[cc[t][1][0]] >= cr[t][1][0]);
            const unsigned long long B3 = __ballot(xw[cc[t][1][1]] >= cr[t][1][1]);
            const unsigned long long B4 = __ballot(xw[cc[t][2][0]] >= cr[t][2][0]);
            const unsigned long long B5 = __ballot(xw[cc[t][2][1]] >= cr[t][2][1]);

            int idx = 0;
            #pragma unroll
            for (int j = 0; j < 6; ++j) {
                const int e = 6 * lane + j;          // even => e&1 == j&1
                const int g = e >> 7;
                const unsigned long long src =
                    (j & 1) ? ((g == 0) ? B1 : (g == 1) ? B3 : B5)
                            : ((g == 0) ? B0 : (g == 1) ? B2 : B4);
                idx |= (int)((src >> ((e & 127) >> 1)) & 1ull) << j;
            }

            const float v = sl[(t * 64 + lane) * LUTSZ + idx];
            yout[(size_t)b * FEAT + f0 + t * 64 + lane] = v;
        }
    }
}

extern "C" void kernel_launch(void* const* d_in, const int* in_sizes, int n_in,
                              void* d_out, int out_size, void* d_ws, size_t ws_size,
                              hipStream_t stream) {
    const float* inputs = (const float*)d_in[0];
    const float* r1     = (const float*)d_in[1];
    const float* r2     = (const float*)d_in[2];
    const float* r3     = (const float*)d_in[3];
    const float* lut1   = (const float*)d_in[4];
    const float* lut2   = (const float*)d_in[5];
    const float* lut3   = (const float*)d_in[6];
    const int*   c1     = (const int*)d_in[7];
    const int*   c2     = (const int*)d_in[8];
    const int*   c3     = (const int*)d_in[9];
    float* out = (float*)d_out;

    const size_t n = (size_t)BATCH * FEAT;
    float* ws1 = (float*)d_ws;        // [BATCH, FEAT] f32 (proven ws window)
    float* ws2 = ws1 + n;

    dim3 grid(FEAT / TF, GROUPS), block(512);
    lut_tile_kernel<0><<<grid, block, 0, stream>>>(inputs, r1, c1, lut1, ws1);
    lut_tile_kernel<1><<<grid, block, 0, stream>>>(ws1,    r2, c2, lut2, ws2);
    lut_tile_kernel<2><<<grid, block, 0, stream>>>(ws2,    r3, c3, lut3, out);
}